// Round 3
// baseline (472.705 us; speedup 1.0000x reference)
//
#include <hip/hip_runtime.h>

typedef float  f32x4  __attribute__((ext_vector_type(4)));
typedef __bf16 bf16x8 __attribute__((ext_vector_type(8)));
typedef __bf16 bf16x4 __attribute__((ext_vector_type(4)));
typedef unsigned short u16;

#define BATCH 2048
#define DM    256
#define NFEAT 32768
#define NBLK  8
#define ALPHA_C   0.99f
#define EPS_CTRL  3e-4f
#define TARGET_L0 100.0f

#define BT    64          // batch rows per workgroup
#define FC    2048        // features per chunk
#define MACRO 256         // features per macro-iter
#define NMACRO (FC / MACRO)

// ---- workspace layout ----
#define WS_RA    0
#define WS_SCALE 1
#define WS_L0    2      // as unsigned
#define WS_L1    4      // 8 floats
#define WS_ERR   16     // 8 floats
#define WS_WDN   256    // 32768 floats
#define WS_PREDS (WS_WDN + NFEAT)
#define PREDS_FLOATS ((size_t)NBLK * BATCH * DM)
#define WS_PRE_BYTES (((size_t)WS_PREDS + PREDS_FLOATS) * 4)
#define WEP_OFF_BYTES WS_PRE_BYTES                         // packed We bf16, 16 MB
#define WDP_OFF_BYTES (WEP_OFF_BYTES + (size_t)NFEAT * DM * 2)  // packed Wd bf16, 16 MB

static __device__ inline u16 f2b(float f) {
    return __builtin_bit_cast(u16, (__bf16)f);
}
static __device__ inline f32x4 mfma16(bf16x8 a, bf16x8 b, f32x4 c) {
    return __builtin_amdgcn_mfma_f32_16x16x32_bf16(a, b, c, 0, 0, 0);
}

// ---------------- small kernels ----------------

__global__ __launch_bounds__(256) void k_rownorm(const float* __restrict__ x, float* ws) {
    const int wave = threadIdx.x >> 6, lane = threadIdx.x & 63;
    const int row = blockIdx.x * 4 + wave;
    const float4 v = *reinterpret_cast<const float4*>(x + (size_t)row * DM + lane * 4);
    float s = v.x * v.x + v.y * v.y + v.z * v.z + v.w * v.w;
    #pragma unroll
    for (int o = 32; o; o >>= 1) s += __shfl_xor(s, o);
    if (lane == 0) atomicAdd(&ws[WS_RA], sqrtf(s));
}

__global__ __launch_bounds__(256) void k_wdn(const float* __restrict__ Wd, float* ws) {
    const int wave = threadIdx.x >> 6, lane = threadIdx.x & 63;
    const int f = blockIdx.x * 4 + wave;
    const float4 v = *reinterpret_cast<const float4*>(Wd + (size_t)f * DM + lane * 4);
    float s = v.x * v.x + v.y * v.y + v.z * v.z + v.w * v.w;
    #pragma unroll
    for (int o = 32; o; o >>= 1) s += __shfl_xor(s, o);
    if (lane == 0) ws[WS_WDN + f] = sqrtf(s);
}

__global__ void k_scale(const float* __restrict__ ravg, float* ws) {
    float ra = ALPHA_C * ravg[0] + (1.0f - ALPHA_C) * (ws[WS_RA] / (float)BATCH);
    ws[WS_SCALE] = 16.0f / ra;   // sqrt(256) = 16
}

// pack We [k][f] -> fragment order: block (F,kf), lane l holds
// We[kf*32+(l>>4)*8+i][F*16+(l&15)], i=0..7, at WeP + ((F*8+kf)*64+l)*8
__global__ __launch_bounds__(256) void k_packWe(const float* __restrict__ We,
                                                u16* __restrict__ WeP) {
    const int tid = blockIdx.x * 256 + threadIdx.x;
    const int l = tid & 63, kf = (tid >> 6) & 7, F = tid >> 9;
    const int f = F * 16 + (l & 15);
    const int kb = kf * 32 + (l >> 4) * 8;
    bf16x8 v;
    #pragma unroll
    for (int i = 0; i < 8; ++i)
        v[i] = (__bf16)We[(size_t)(kb + i) * NFEAT + f];
    *reinterpret_cast<bf16x8*>(WeP + (size_t)tid * 8) = v;
}

// pack Wd [f][d] -> fragment order: block (Dg,G), lane l holds
// Wd[G*32+(l>>4)*8+i][Dg*16+(l&15)], at WdP + ((Dg*1024+G)*64+l)*8
__global__ __launch_bounds__(256) void k_packWd(const float* __restrict__ Wd,
                                                u16* __restrict__ WdP) {
    const int tid = blockIdx.x * 256 + threadIdx.x;
    const int l = tid & 63, G = (tid >> 6) & 1023, Dg = tid >> 16;
    const int d = Dg * 16 + (l & 15);
    const int fb = G * 32 + (l >> 4) * 8;
    bf16x8 v;
    #pragma unroll
    for (int i = 0; i < 8; ++i)
        v[i] = (__bf16)Wd[(size_t)(fb + i) * DM + d];
    *reinterpret_cast<bf16x8*>(WdP + (size_t)tid * 8) = v;
}

// ---------------- fused main kernel ----------------
// 512 threads = 8 waves. grid (btile=BATCH/BT, chunk=NFEAT/FC) so that all
// chunks of one btile share an XCD (linear id = btile + 32*chunk).
// encode: wave w owns feats [32w,32w+32) of each 256-feat macro. eacc[4][2].
// decode: wave w owns out cols [32w,32w+32). pacc[4][2] persistent.
// LDS xs/acts in MFMA-fragment packed order: elem((row,c)) =
//   (( (row>>4)*8 + (c>>5) )*64 + ((c>>3)&3)*16 + (row&15))*8 + (c&7)
__global__ __launch_bounds__(512, 3) void k_main(const float* __restrict__ x,
                                                 const float* __restrict__ be,
                                                 const int* __restrict__ seg,
                                                 float* __restrict__ ws,
                                                 const u16* __restrict__ WeP,
                                                 const u16* __restrict__ WdP) {
    __shared__ __align__(16) u16 xs[BT * DM];       // 32 KB packed
    __shared__ __align__(16) u16 acts[BT * MACRO];  // 32 KB packed
    __shared__ float lds_l1[NBLK];
    __shared__ unsigned lds_l0;

    const int t = threadIdx.x;
    const int w = t >> 6;           // 0..7
    const int l = t & 63;
    const int l15 = l & 15, lg = l >> 4;
    const int b0 = blockIdx.x * BT;
    const int f0 = blockIdx.y * FC;
    const float scale = ws[WS_SCALE];
    float* preds = ws + WS_PREDS;

    if (t < NBLK) lds_l1[t] = 0.0f;
    if (t == 0) lds_l0 = 0u;

    // stage xn = x*scale, packed bf16
    #pragma unroll
    for (int p = 0; p < 8; ++p) {
        const int row = p * 8 + (t >> 6);
        const int col = (t & 63) * 4;
        const float4 v = *reinterpret_cast<const float4*>(x + (size_t)(b0 + row) * DM + col);
        bf16x4 h;
        h[0] = (__bf16)(v.x * scale); h[1] = (__bf16)(v.y * scale);
        h[2] = (__bf16)(v.z * scale); h[3] = (__bf16)(v.w * scale);
        const int e = (((row >> 4) * 8 + (col >> 5)) * 64 + ((col >> 3) & 3) * 16 + (row & 15)) * 8 + (col & 7);
        *reinterpret_cast<bf16x4*>(&xs[e]) = h;
    }
    __syncthreads();

    f32x4 pacc[4][2];
    #pragma unroll
    for (int i = 0; i < 4; ++i)
        #pragma unroll
        for (int j = 0; j < 2; ++j) pacc[i][j] = (f32x4)0.0f;

    int cur = seg[f0];
    float l1a = 0.0f;
    int myseg = -1;
    unsigned l0c = 0u;

    auto flush = [&](int s) {
        float* pb = preds + (size_t)s * BATCH * DM;
        #pragma unroll
        for (int rt = 0; rt < 4; ++rt)
            #pragma unroll
            for (int ct = 0; ct < 2; ++ct)
                #pragma unroll
                for (int r = 0; r < 4; ++r) {
                    const int row = b0 + 16 * rt + lg * 4 + r;
                    const int col = 32 * w + 16 * ct + l15;
                    atomicAdd(&pb[(size_t)row * DM + col], pacc[rt][ct][r]);
                    pacc[rt][ct][r] = 0.0f;
                }
    };

    for (int ms = 0; ms < NMACRO; ++ms) {
        const int fbase = f0 + ms * MACRO;
        const bool uni = (seg[fbase] == seg[fbase + MACRO - 1]);

        // ---- encode ----
        f32x4 eacc[4][2];
        #pragma unroll
        for (int i = 0; i < 4; ++i)
            #pragma unroll
            for (int j = 0; j < 2; ++j) eacc[i][j] = (f32x4)0.0f;

        const int F0 = (fbase >> 4) + 2 * w;   // WeP 16-feature group base for this wave
        #pragma unroll
        for (int kf = 0; kf < 8; ++kf) {
            bf16x8 a[4], b[2];
            #pragma unroll
            for (int rt = 0; rt < 4; ++rt)
                a[rt] = *reinterpret_cast<const bf16x8*>(&xs[((rt * 8 + kf) * 64 + l) * 8]);
            #pragma unroll
            for (int ct = 0; ct < 2; ++ct)
                b[ct] = *reinterpret_cast<const bf16x8*>(WeP + (((size_t)(F0 + ct) * 8 + kf) * 64 + l) * 8);
            #pragma unroll
            for (int rt = 0; rt < 4; ++rt)
                #pragma unroll
                for (int ct = 0; ct < 2; ++ct)
                    eacc[rt][ct] = mfma16(a[rt], b[ct], eacc[rt][ct]);
        }

        // ---- epilogue: bias, relu, l1/l0, acts -> LDS packed bf16 ----
        #pragma unroll
        for (int ct = 0; ct < 2; ++ct) {
            const int fg = fbase + 32 * w + 16 * ct + l15;
            const float bias = be[fg];
            const float wdn10 = ws[WS_WDN + fg] * 10.0f;
            const int s = uni ? seg[fbase] : seg[fg];
            if (s != myseg) {
                if (myseg >= 0) atomicAdd(&lds_l1[myseg], l1a);
                l1a = 0.0f; myseg = s;
            }
            const int ebase = ((16 * ct + l15) >> 3) * 16 + (l15 & 7) - 8 * w * 64; // helper below
            #pragma unroll
            for (int rt = 0; rt < 4; ++rt)
                #pragma unroll
                for (int r = 0; r < 4; ++r) {
                    float a = eacc[rt][ct][r] + bias;
                    a = fmaxf(a, 0.0f);
                    l0c += (a > 0.0f) ? 1u : 0u;
                    l1a += __logf(fmaf(a, wdn10, 1.0f));
                    const int e = ((rt * 8 + w) * 64 + ((16 * ct + l15) >> 3) * 16 + lg * 4 + r) * 8 + (l15 & 7);
                    acts[e] = f2b(a);
                }
        }
        (void)0;
        __syncthreads();   // acts visible

        // ---- decode ----
        const int Dg0 = 2 * w;
        const int G0 = fbase >> 5;
        if (uni) {
            const int s = seg[fbase];
            if (s != cur) { flush(cur); cur = s; }
            #pragma unroll
            for (int kf = 0; kf < 8; ++kf) {
                bf16x8 a[4], b[2];
                #pragma unroll
                for (int rt = 0; rt < 4; ++rt)
                    a[rt] = *reinterpret_cast<const bf16x8*>(&acts[((rt * 8 + kf) * 64 + l) * 8]);
                #pragma unroll
                for (int ct = 0; ct < 2; ++ct)
                    b[ct] = *reinterpret_cast<const bf16x8*>(WdP + (((size_t)(Dg0 + ct) * 1024 + G0 + kf) * 64 + l) * 8);
                #pragma unroll
                for (int rt = 0; rt < 4; ++rt)
                    #pragma unroll
                    for (int ct = 0; ct < 2; ++ct)
                        pacc[rt][ct] = mfma16(a[rt], b[ct], pacc[rt][ct]);
            }
        } else {
            for (int kf = 0; kf < 8; ++kf) {
                const int W0 = fbase + kf * 32;
                const int s0 = seg[W0], s1 = seg[W0 + 31];
                bf16x8 b[2];
                #pragma unroll
                for (int ct = 0; ct < 2; ++ct)
                    b[ct] = *reinterpret_cast<const bf16x8*>(WdP + (((size_t)(Dg0 + ct) * 1024 + G0 + kf) * 64 + l) * 8);
                if (s0 == s1) {
                    if (s0 != cur) { flush(cur); cur = s0; }
                    bf16x8 a[4];
                    #pragma unroll
                    for (int rt = 0; rt < 4; ++rt)
                        a[rt] = *reinterpret_cast<const bf16x8*>(&acts[((rt * 8 + kf) * 64 + l) * 8]);
                    #pragma unroll
                    for (int rt = 0; rt < 4; ++rt)
                        #pragma unroll
                        for (int ct = 0; ct < 2; ++ct)
                            pacc[rt][ct] = mfma16(a[rt], b[ct], pacc[rt][ct]);
                } else {
                    int lo = 0;
                    while (lo < 32) {
                        const int s = seg[W0 + lo];
                        int hi = lo + 1;
                        while (hi < 32 && seg[W0 + hi] == s) ++hi;
                        if (s != cur) { flush(cur); cur = s; }
                        bf16x8 a[4];
                        #pragma unroll
                        for (int rt = 0; rt < 4; ++rt) {
                            a[rt] = *reinterpret_cast<const bf16x8*>(&acts[((rt * 8 + kf) * 64 + l) * 8]);
                            #pragma unroll
                            for (int i = 0; i < 8; ++i) {
                                const int kl = lg * 8 + i;
                                if (kl < lo || kl >= hi) a[rt][i] = (__bf16)0.0f;
                            }
                        }
                        #pragma unroll
                        for (int rt = 0; rt < 4; ++rt)
                            #pragma unroll
                            for (int ct = 0; ct < 2; ++ct)
                                pacc[rt][ct] = mfma16(a[rt], b[ct], pacc[rt][ct]);
                        lo = hi;
                    }
                }
            }
        }
        __syncthreads();   // decode reads done before next macro overwrites acts
    }

    flush(cur);
    if (myseg >= 0) atomicAdd(&lds_l1[myseg], l1a);
    atomicAdd(&lds_l0, l0c);
    __syncthreads();
    if (t < NBLK) atomicAdd(&ws[WS_L1 + t], lds_l1[t]);
    if (t == 0) atomicAdd(((unsigned*)ws) + WS_L0, lds_l0);
}

// ---------------- epilogue kernels ----------------

__global__ __launch_bounds__(256) void k_err(const float* __restrict__ x,
                                             const float* __restrict__ bd,
                                             float* ws) {
    const int b = blockIdx.x, t = threadIdx.x;
    const int wave = t >> 6, lane = t & 63;
    const float* preds = ws + WS_PREDS;
    const float scale = ws[WS_SCALE];
    const float xv = x[(size_t)b * DM + t] * scale;
    float p = bd[t];
    __shared__ float lds[NBLK][4];
    for (int k = 0; k < NBLK; ++k) {
        p += preds[(size_t)k * BATCH * DM + (size_t)b * DM + t];
        const float d = p - xv;
        float e = d * d;
        #pragma unroll
        for (int o = 32; o; o >>= 1) e += __shfl_xor(e, o);
        if (lane == 0) lds[k][wave] = e;
    }
    __syncthreads();
    if (t < NBLK) {
        const float s = lds[t][0] + lds[t][1] + lds[t][2] + lds[t][3];
        atomicAdd(&ws[WS_ERR + t], s);
    }
}

__global__ void k_loss(const float* __restrict__ bw,
                       const float* __restrict__ l1s,
                       const float* ws, float* out) {
    float cum = 0.0f, l1 = 0.0f, mse = 0.0f;
    for (int k = 0; k < NBLK; ++k) {
        cum += ws[WS_L1 + k] / (float)BATCH;
        l1 += bw[k] * cum;
        mse += bw[k] * (ws[WS_ERR + k] / (float)BATCH);
    }
    l1 *= (1.0f / NBLK);
    mse *= (1.0f / NBLK);
    const unsigned l0 = ((const unsigned*)ws)[WS_L0];
    const float avg_l0 = (float)l0 / (float)BATCH;
    const float rs = l1s[0] * (avg_l0 < TARGET_L0 ? (1.0f - EPS_CTRL) : (1.0f + EPS_CTRL));
    out[0] = mse + rs * l1;
}

// ---------------- launch ----------------

extern "C" void kernel_launch(void* const* d_in, const int* in_sizes, int n_in,
                              void* d_out, int out_size, void* d_ws, size_t ws_size,
                              hipStream_t stream) {
    const float* x    = (const float*)d_in[0];
    const float* We   = (const float*)d_in[1];
    const float* be   = (const float*)d_in[2];
    const float* Wd   = (const float*)d_in[3];
    const float* bd   = (const float*)d_in[4];
    const float* bw   = (const float*)d_in[5];
    const float* ravg = (const float*)d_in[6];
    const float* l1s  = (const float*)d_in[7];
    const int*   seg  = (const int*)d_in[8];
    float* out = (float*)d_out;
    float* ws  = (float*)d_ws;
    u16* WeP = (u16*)((char*)d_ws + WEP_OFF_BYTES);
    u16* WdP = (u16*)((char*)d_ws + WDP_OFF_BYTES);

    hipMemsetAsync(d_ws, 0, WS_PRE_BYTES, stream);
    k_rownorm<<<BATCH / 4, 256, 0, stream>>>(x, ws);
    k_wdn<<<NFEAT / 4, 256, 0, stream>>>(Wd, ws);
    k_packWe<<<(NFEAT / 16) * 8 * 64 / 256, 256, 0, stream>>>(We, WeP);
    k_packWd<<<(DM / 16) * (NFEAT / 32) * 64 / 256, 256, 0, stream>>>(Wd, WdP);
    k_scale<<<1, 1, 0, stream>>>(ravg, ws);
    dim3 g(BATCH / BT, NFEAT / FC);   // x=btile, y=chunk -> same-XCD atomics per btile
    k_main<<<g, 512, 0, stream>>>(x, be, seg, ws, WeP, WdP);
    k_err<<<BATCH, 256, 0, stream>>>(x, bd, ws);
    k_loss<<<1, 1, 0, stream>>>(bw, l1s, ws, out);
}

// Round 4
// 394.763 us; speedup vs baseline: 1.1974x; 1.1974x over previous
//
#include <hip/hip_runtime.h>

typedef float  f32x4  __attribute__((ext_vector_type(4)));
typedef __bf16 bf16x8 __attribute__((ext_vector_type(8)));
typedef __bf16 bf16x4 __attribute__((ext_vector_type(4)));
typedef unsigned short u16;

#define BATCH 2048
#define DM    256
#define NFEAT 32768
#define NBLK  8
#define ALPHA_C   0.99f
#define EPS_CTRL  3e-4f
#define TARGET_L0 100.0f

#define BT    64          // batch rows per workgroup
#define FC    2048        // features per chunk
#define NCHUNK (NFEAT / FC)
#define MACRO 256         // features per macro-iter
#define NMACRO (FC / MACRO)
#define NPMAX 24          // max pieces = 16 chunks + 7 seg boundaries

// ---- workspace layout ----
// float region (misc): 0..33023 floats
#define WS_RA    0
#define WS_SCALE 1
#define WS_L0    2      // as unsigned
#define WS_L1    4      // 8 floats
#define WS_ERR   16     // 8 floats
// int views (offsets in int units within ws):
#define WSI_BND  32     // 8 ints: first feature of segment s (s>=1 written)
#define WSI_PTN  40     // piece count N
#define WSI_PTS  41     // N+1 piece start features
#define WSI_PSEG 66     // N piece segment ids
#define WS_WDN   256    // 32768 floats
// byte offsets for big regions:
#define PIECES_OFF_BYTES ((size_t)262144)                         // 256 KB
#define PIECES_BYTES ((size_t)NPMAX * BATCH * DM * 2)             // 24 MB bf16
#define WEP_OFF_BYTES (PIECES_OFF_BYTES + PIECES_BYTES)
#define WDP_OFF_BYTES (WEP_OFF_BYTES + (size_t)NFEAT * DM * 2)    // +16 MB

static __device__ inline u16 f2b(float f) {
    return __builtin_bit_cast(u16, (__bf16)f);
}
static __device__ inline float b2f(u16 u) {
    return (float)__builtin_bit_cast(__bf16, u);
}
static __device__ inline f32x4 mfma16(bf16x8 a, bf16x8 b, f32x4 c) {
    return __builtin_amdgcn_mfma_f32_16x16x32_bf16(a, b, c, 0, 0, 0);
}

// ---------------- small kernels ----------------

__global__ __launch_bounds__(256) void k_rownorm(const float* __restrict__ x, float* ws) {
    const int wave = threadIdx.x >> 6, lane = threadIdx.x & 63;
    const int row = blockIdx.x * 4 + wave;
    const float4 v = *reinterpret_cast<const float4*>(x + (size_t)row * DM + lane * 4);
    float s = v.x * v.x + v.y * v.y + v.z * v.z + v.w * v.w;
    #pragma unroll
    for (int o = 32; o; o >>= 1) s += __shfl_xor(s, o);
    if (lane == 0) atomicAdd(&ws[WS_RA], sqrtf(s));
}

__global__ __launch_bounds__(256) void k_wdn(const float* __restrict__ Wd, float* ws) {
    const int wave = threadIdx.x >> 6, lane = threadIdx.x & 63;
    const int f = blockIdx.x * 4 + wave;
    const float4 v = *reinterpret_cast<const float4*>(Wd + (size_t)f * DM + lane * 4);
    float s = v.x * v.x + v.y * v.y + v.z * v.z + v.w * v.w;
    #pragma unroll
    for (int o = 32; o; o >>= 1) s += __shfl_xor(s, o);
    if (lane == 0) ws[WS_WDN + f] = sqrtf(s);
}

__global__ void k_scale(const float* __restrict__ ravg, float* ws) {
    float ra = ALPHA_C * ravg[0] + (1.0f - ALPHA_C) * (ws[WS_RA] / (float)BATCH);
    ws[WS_SCALE] = 16.0f / ra;   // sqrt(256) = 16
}

// find segment boundary positions: bnd[s] = first feature of segment s
__global__ __launch_bounds__(256) void k_bnd(const int* __restrict__ seg, int* wsi) {
    const int f = blockIdx.x * 256 + threadIdx.x;
    if (f > 0 && f < NFEAT) {
        const int s = seg[f];
        if (s != seg[f - 1]) wsi[WSI_BND + s] = f;
    }
}

// build piece table: sorted dedup of {chunk starts} U {segment boundaries}
__global__ void k_pt(const int* __restrict__ seg, int* wsi) {
    int st[NCHUNK + NBLK - 1];
    int n = 0;
    for (int c = 0; c < NCHUNK; ++c) st[n++] = c * FC;
    for (int s = 1; s < NBLK; ++s) st[n++] = wsi[WSI_BND + s];
    for (int i = 1; i < n; ++i) {           // insertion sort
        int v = st[i]; int j = i - 1;
        while (j >= 0 && st[j] > v) { st[j + 1] = st[j]; --j; }
        st[j + 1] = v;
    }
    int N = 0;                               // dedup in place
    for (int i = 0; i < n; ++i)
        if (N == 0 || st[i] != st[N - 1]) st[N++] = st[i];
    wsi[WSI_PTN] = N;
    for (int i = 0; i < N; ++i) {
        wsi[WSI_PTS + i] = st[i];
        wsi[WSI_PSEG + i] = seg[st[i]];
    }
    wsi[WSI_PTS + N] = NFEAT;
}

// pack We [k][f] -> fragment order (see round-3 layout, verified)
__global__ __launch_bounds__(256) void k_packWe(const float* __restrict__ We,
                                                u16* __restrict__ WeP) {
    const int tid = blockIdx.x * 256 + threadIdx.x;
    const int l = tid & 63, kf = (tid >> 6) & 7, F = tid >> 9;
    const int f = F * 16 + (l & 15);
    const int kb = kf * 32 + (l >> 4) * 8;
    bf16x8 v;
    #pragma unroll
    for (int i = 0; i < 8; ++i)
        v[i] = (__bf16)We[(size_t)(kb + i) * NFEAT + f];
    *reinterpret_cast<bf16x8*>(WeP + (size_t)tid * 8) = v;
}

__global__ __launch_bounds__(256) void k_packWd(const float* __restrict__ Wd,
                                                u16* __restrict__ WdP) {
    const int tid = blockIdx.x * 256 + threadIdx.x;
    const int l = tid & 63, G = (tid >> 6) & 1023, Dg = tid >> 16;
    const int d = Dg * 16 + (l & 15);
    const int fb = G * 32 + (l >> 4) * 8;
    bf16x8 v;
    #pragma unroll
    for (int i = 0; i < 8; ++i)
        v[i] = (__bf16)Wd[(size_t)(fb + i) * DM + d];
    *reinterpret_cast<bf16x8*>(WdP + (size_t)tid * 8) = v;
}

// ---------------- fused main kernel ----------------
// grid (chunk=16, btile=32): linear id = chunk + 16*btile -> XCD = chunk%8,
// so each XCD serves 2 chunks (4 MB packed weights) = L2-resident.
// 512 threads = 8 waves. encode: wave w owns feats [32w,32w+32) per macro.
// decode: wave w owns out cols [32w,32w+32); pacc stored (not atomic) into
// this block's unique piece slots at piece boundaries.
__global__ __launch_bounds__(512, 4) void k_main(const float* __restrict__ x,
                                                 const float* __restrict__ be,
                                                 const int* __restrict__ seg,
                                                 float* __restrict__ ws,
                                                 u16* __restrict__ pieces,
                                                 const u16* __restrict__ WeP,
                                                 const u16* __restrict__ WdP) {
    __shared__ __align__(16) u16 xs[BT * DM];       // 32 KB packed
    __shared__ __align__(16) u16 acts[BT * MACRO];  // 32 KB packed
    __shared__ float lds_l1[NBLK];
    __shared__ unsigned lds_l0;
    __shared__ int s2s[NBLK];                       // seg -> piece slot (this chunk)

    const int t = threadIdx.x;
    const int w = t >> 6;           // 0..7
    const int l = t & 63;
    const int l15 = l & 15, lg = l >> 4;
    const int f0 = blockIdx.x * FC;
    const int b0 = blockIdx.y * BT;
    const float scale = ws[WS_SCALE];
    const int* wsi = (const int*)ws;

    if (t < NBLK) lds_l1[t] = 0.0f;
    if (t == 0) lds_l0 = 0u;
    if (t < NPMAX) {
        const int N = wsi[WSI_PTN];
        if (t < N) {
            const int ps = wsi[WSI_PTS + t];
            if (ps >= f0 && ps < f0 + FC) s2s[wsi[WSI_PSEG + t]] = t;
        }
    }

    // stage xn = x*scale, packed bf16
    #pragma unroll
    for (int p = 0; p < 8; ++p) {
        const int row = p * 8 + (t >> 6);
        const int col = (t & 63) * 4;
        const float4 v = *reinterpret_cast<const float4*>(x + (size_t)(b0 + row) * DM + col);
        bf16x4 h;
        h[0] = (__bf16)(v.x * scale); h[1] = (__bf16)(v.y * scale);
        h[2] = (__bf16)(v.z * scale); h[3] = (__bf16)(v.w * scale);
        const int e = (((row >> 4) * 8 + (col >> 5)) * 64 + ((col >> 3) & 3) * 16 + (row & 15)) * 8 + (col & 7);
        *reinterpret_cast<bf16x4*>(&xs[e]) = h;
    }
    __syncthreads();

    f32x4 pacc[4][2];
    #pragma unroll
    for (int i = 0; i < 4; ++i)
        #pragma unroll
        for (int j = 0; j < 2; ++j) pacc[i][j] = (f32x4)0.0f;

    int cur = seg[f0];
    float l1a = 0.0f;
    int myseg = -1;
    unsigned l0c = 0u;

    // store this segment's partial into its unique piece slot (sole writer)
    auto flush = [&](int s) {
        u16* pb = pieces + (size_t)s2s[s] * (BATCH * DM);
        #pragma unroll
        for (int rt = 0; rt < 4; ++rt)
            #pragma unroll
            for (int ct = 0; ct < 2; ++ct)
                #pragma unroll
                for (int r = 0; r < 4; ++r) {
                    const int row = b0 + 16 * rt + lg * 4 + r;
                    const int col = 32 * w + 16 * ct + l15;
                    pb[(size_t)row * DM + col] = f2b(pacc[rt][ct][r]);
                    pacc[rt][ct][r] = 0.0f;
                }
    };

    for (int ms = 0; ms < NMACRO; ++ms) {
        const int fbase = f0 + ms * MACRO;
        const bool uni = (seg[fbase] == seg[fbase + MACRO - 1]);

        // ---- encode (depth-2 B prefetch) ----
        f32x4 eacc[4][2];
        #pragma unroll
        for (int i = 0; i < 4; ++i)
            #pragma unroll
            for (int j = 0; j < 2; ++j) eacc[i][j] = (f32x4)0.0f;

        const int F0 = (fbase >> 4) + 2 * w;
        auto ldWe = [&](int kf, int ct) {
            return *reinterpret_cast<const bf16x8*>(WeP + (((size_t)(F0 + ct) * 8 + kf) * 64 + l) * 8);
        };
        bf16x8 bn0 = ldWe(0, 0), bn1 = ldWe(0, 1);
        #pragma unroll
        for (int kf = 0; kf < 8; ++kf) {
            const bf16x8 bc0 = bn0, bc1 = bn1;
            if (kf < 7) { bn0 = ldWe(kf + 1, 0); bn1 = ldWe(kf + 1, 1); }
            bf16x8 a[4];
            #pragma unroll
            for (int rt = 0; rt < 4; ++rt)
                a[rt] = *reinterpret_cast<const bf16x8*>(&xs[((rt * 8 + kf) * 64 + l) * 8]);
            #pragma unroll
            for (int rt = 0; rt < 4; ++rt) {
                eacc[rt][0] = mfma16(a[rt], bc0, eacc[rt][0]);
                eacc[rt][1] = mfma16(a[rt], bc1, eacc[rt][1]);
            }
        }

        // ---- epilogue: bias, relu, l1/l0, acts -> LDS packed bf16 ----
        #pragma unroll
        for (int ct = 0; ct < 2; ++ct) {
            const int fg = fbase + 32 * w + 16 * ct + l15;
            const float bias = be[fg];
            const float wdn10 = ws[WS_WDN + fg] * 10.0f;
            const int s = uni ? seg[fbase] : seg[fg];
            if (s != myseg) {
                if (myseg >= 0) atomicAdd(&lds_l1[myseg], l1a);
                l1a = 0.0f; myseg = s;
            }
            #pragma unroll
            for (int rt = 0; rt < 4; ++rt)
                #pragma unroll
                for (int r = 0; r < 4; ++r) {
                    float a = eacc[rt][ct][r] + bias;
                    a = fmaxf(a, 0.0f);
                    l0c += (a > 0.0f) ? 1u : 0u;
                    l1a += __logf(fmaf(a, wdn10, 1.0f));
                    const int e = ((rt * 8 + w) * 64 + ((16 * ct + l15) >> 3) * 16 + lg * 4 + r) * 8 + (l15 & 7);
                    acts[e] = f2b(a);
                }
        }
        __syncthreads();   // acts visible

        // ---- decode ----
        const int Dg0 = 2 * w;
        const int G0 = fbase >> 5;
        auto ldWd = [&](int kf, int ct) {
            return *reinterpret_cast<const bf16x8*>(WdP + (((size_t)(Dg0 + ct) * 1024 + G0 + kf) * 64 + l) * 8);
        };
        if (uni) {
            const int s = seg[fbase];
            if (s != cur) { flush(cur); cur = s; }
            bf16x8 dn0 = ldWd(0, 0), dn1 = ldWd(0, 1);
            #pragma unroll
            for (int kf = 0; kf < 8; ++kf) {
                const bf16x8 dc0 = dn0, dc1 = dn1;
                if (kf < 7) { dn0 = ldWd(kf + 1, 0); dn1 = ldWd(kf + 1, 1); }
                bf16x8 a[4];
                #pragma unroll
                for (int rt = 0; rt < 4; ++rt)
                    a[rt] = *reinterpret_cast<const bf16x8*>(&acts[((rt * 8 + kf) * 64 + l) * 8]);
                #pragma unroll
                for (int rt = 0; rt < 4; ++rt) {
                    pacc[rt][0] = mfma16(a[rt], dc0, pacc[rt][0]);
                    pacc[rt][1] = mfma16(a[rt], dc1, pacc[rt][1]);
                }
            }
        } else {
            for (int kf = 0; kf < 8; ++kf) {
                const int W0 = fbase + kf * 32;
                const int s0 = seg[W0], s1 = seg[W0 + 31];
                bf16x8 b[2];
                #pragma unroll
                for (int ct = 0; ct < 2; ++ct) b[ct] = ldWd(kf, ct);
                if (s0 == s1) {
                    if (s0 != cur) { flush(cur); cur = s0; }
                    bf16x8 a[4];
                    #pragma unroll
                    for (int rt = 0; rt < 4; ++rt)
                        a[rt] = *reinterpret_cast<const bf16x8*>(&acts[((rt * 8 + kf) * 64 + l) * 8]);
                    #pragma unroll
                    for (int rt = 0; rt < 4; ++rt) {
                        pacc[rt][0] = mfma16(a[rt], b[0], pacc[rt][0]);
                        pacc[rt][1] = mfma16(a[rt], b[1], pacc[rt][1]);
                    }
                } else {
                    int lo = 0;
                    while (lo < 32) {
                        const int s = seg[W0 + lo];
                        int hi = lo + 1;
                        while (hi < 32 && seg[W0 + hi] == s) ++hi;
                        if (s != cur) { flush(cur); cur = s; }
                        bf16x8 a[4];
                        #pragma unroll
                        for (int rt = 0; rt < 4; ++rt) {
                            a[rt] = *reinterpret_cast<const bf16x8*>(&acts[((rt * 8 + kf) * 64 + l) * 8]);
                            #pragma unroll
                            for (int i = 0; i < 8; ++i) {
                                const int kl = lg * 8 + i;
                                if (kl < lo || kl >= hi) a[rt][i] = (__bf16)0.0f;
                            }
                        }
                        #pragma unroll
                        for (int rt = 0; rt < 4; ++rt) {
                            pacc[rt][0] = mfma16(a[rt], b[0], pacc[rt][0]);
                            pacc[rt][1] = mfma16(a[rt], b[1], pacc[rt][1]);
                        }
                        lo = hi;
                    }
                }
            }
        }
        __syncthreads();   // decode reads done before next macro overwrites acts
    }

    flush(cur);
    if (myseg >= 0) atomicAdd(&lds_l1[myseg], l1a);
    atomicAdd(&lds_l0, l0c);
    __syncthreads();
    if (t < NBLK) atomicAdd(&ws[WS_L1 + t], lds_l1[t]);
    if (t == 0) atomicAdd(((unsigned*)ws) + WS_L0, lds_l0);
}

// ---------------- epilogue kernels ----------------

// walk pieces in feature order, accumulate cumsum, snapshot err at segment ends
__global__ __launch_bounds__(256) void k_err(const float* __restrict__ x,
                                             const float* __restrict__ bd,
                                             float* ws,
                                             const u16* __restrict__ pieces) {
    const int b = blockIdx.x, t = threadIdx.x;
    const int wave = t >> 6, lane = t & 63;
    const int* wsi = (const int*)ws;
    const int N = wsi[WSI_PTN];
    const float scale = ws[WS_SCALE];
    const float xv = x[(size_t)b * DM + t] * scale;
    float p = bd[t];
    __shared__ float lds[NBLK][4];
    for (int i = 0; i < N; ++i) {
        p += b2f(pieces[(size_t)i * (BATCH * DM) + (size_t)b * DM + t]);
        const int sg = wsi[WSI_PSEG + i];
        const bool end = (i == N - 1) || (wsi[WSI_PSEG + i + 1] != sg);
        if (end) {
            const float d = p - xv;
            float e = d * d;
            #pragma unroll
            for (int o = 32; o; o >>= 1) e += __shfl_xor(e, o);
            if (lane == 0) lds[sg][wave] = e;
        }
    }
    __syncthreads();
    if (t < NBLK) {
        const float s = lds[t][0] + lds[t][1] + lds[t][2] + lds[t][3];
        atomicAdd(&ws[WS_ERR + t], s);
    }
}

__global__ void k_loss(const float* __restrict__ bw,
                       const float* __restrict__ l1s,
                       const float* ws, float* out) {
    float cum = 0.0f, l1 = 0.0f, mse = 0.0f;
    for (int k = 0; k < NBLK; ++k) {
        cum += ws[WS_L1 + k] / (float)BATCH;
        l1 += bw[k] * cum;
        mse += bw[k] * (ws[WS_ERR + k] / (float)BATCH);
    }
    l1 *= (1.0f / NBLK);
    mse *= (1.0f / NBLK);
    const unsigned l0 = ((const unsigned*)ws)[WS_L0];
    const float avg_l0 = (float)l0 / (float)BATCH;
    const float rs = l1s[0] * (avg_l0 < TARGET_L0 ? (1.0f - EPS_CTRL) : (1.0f + EPS_CTRL));
    out[0] = mse + rs * l1;
}

// ---------------- launch ----------------

extern "C" void kernel_launch(void* const* d_in, const int* in_sizes, int n_in,
                              void* d_out, int out_size, void* d_ws, size_t ws_size,
                              hipStream_t stream) {
    const float* x    = (const float*)d_in[0];
    const float* We   = (const float*)d_in[1];
    const float* be   = (const float*)d_in[2];
    const float* Wd   = (const float*)d_in[3];
    const float* bd   = (const float*)d_in[4];
    const float* bw   = (const float*)d_in[5];
    const float* ravg = (const float*)d_in[6];
    const float* l1s  = (const float*)d_in[7];
    const int*   seg  = (const int*)d_in[8];
    float* out = (float*)d_out;
    float* ws  = (float*)d_ws;
    int*   wsi = (int*)d_ws;
    u16* pieces = (u16*)((char*)d_ws + PIECES_OFF_BYTES);
    u16* WeP = (u16*)((char*)d_ws + WEP_OFF_BYTES);
    u16* WdP = (u16*)((char*)d_ws + WDP_OFF_BYTES);

    hipMemsetAsync(d_ws, 0, 1024, stream);           // zero accumulators only
    k_bnd<<<NFEAT / 256, 256, 0, stream>>>(seg, wsi);
    k_pt<<<1, 1, 0, stream>>>(seg, wsi);
    k_rownorm<<<BATCH / 4, 256, 0, stream>>>(x, ws);
    k_wdn<<<NFEAT / 4, 256, 0, stream>>>(Wd, ws);
    k_packWe<<<(NFEAT / 16) * 8 * 64 / 256, 256, 0, stream>>>(We, WeP);
    k_packWd<<<(DM / 16) * (NFEAT / 32) * 64 / 256, 256, 0, stream>>>(Wd, WdP);
    k_scale<<<1, 1, 0, stream>>>(ravg, ws);
    dim3 g(NFEAT / FC, BATCH / BT);   // chunk-fast -> XCD = chunk%8 (L2-fit weights)
    k_main<<<g, 512, 0, stream>>>(x, be, seg, ws, pieces, WeP, WdP);
    k_err<<<BATCH, 256, 0, stream>>>(x, bd, ws, pieces);
    k_loss<<<1, 1, 0, stream>>>(bw, l1s, ws, out);
}

// Round 5
// 296.523 us; speedup vs baseline: 1.5942x; 1.3313x over previous
//
#include <hip/hip_runtime.h>

typedef float  f32x4  __attribute__((ext_vector_type(4)));
typedef __bf16 bf16x8 __attribute__((ext_vector_type(8)));
typedef __bf16 bf16x4 __attribute__((ext_vector_type(4)));
typedef unsigned short u16;

#define BATCH 2048
#define DM    256
#define NFEAT 32768
#define NBLK  8
#define ALPHA_C   0.99f
#define EPS_CTRL  3e-4f
#define TARGET_L0 100.0f

#define BT    64          // batch rows per workgroup
#define FC    2048        // features per chunk
#define NCHUNK (NFEAT / FC)
#define MACRO 256         // features per macro-iter
#define NMACRO (FC / MACRO)
#define NPMAX 24          // max pieces = 16 chunks + 7 seg boundaries

// ---- workspace layout ----
#define WS_RA    0
#define WS_SCALE 1
#define WS_L0    2      // as unsigned
#define WS_L1    4      // 8 floats
#define WS_ERR   16     // 8 floats
#define WSI_BND  32     // 8 ints: first feature of segment s (s>=1 written)
#define WSI_PTN  40     // piece count N
#define WSI_PTS  41     // N+1 piece start features
#define WSI_PSEG 66     // N piece segment ids
#define WS_WDN   256    // 32768 floats
#define PIECES_OFF_BYTES ((size_t)262144)                         // 256 KB
#define PIECES_BYTES ((size_t)NPMAX * BATCH * DM * 2)             // 24 MB bf16
#define WEP_OFF_BYTES (PIECES_OFF_BYTES + PIECES_BYTES)
#define WDP_OFF_BYTES (WEP_OFF_BYTES + (size_t)NFEAT * DM * 2)    // +16 MB

static __device__ inline u16 f2b(float f) {
    return __builtin_bit_cast(u16, (__bf16)f);
}
static __device__ inline float b2f(u16 u) {
    return (float)__builtin_bit_cast(__bf16, u);
}
static __device__ inline f32x4 mfma16(bf16x8 a, bf16x8 b, f32x4 c) {
    return __builtin_amdgcn_mfma_f32_16x16x32_bf16(a, b, c, 0, 0, 0);
}

// ---------------- small kernels ----------------

__global__ __launch_bounds__(256) void k_rownorm(const float* __restrict__ x, float* ws) {
    const int wave = threadIdx.x >> 6, lane = threadIdx.x & 63;
    const int row = blockIdx.x * 4 + wave;
    const float4 v = *reinterpret_cast<const float4*>(x + (size_t)row * DM + lane * 4);
    float s = v.x * v.x + v.y * v.y + v.z * v.z + v.w * v.w;
    #pragma unroll
    for (int o = 32; o; o >>= 1) s += __shfl_xor(s, o);
    if (lane == 0) atomicAdd(&ws[WS_RA], sqrtf(s));
}

__global__ __launch_bounds__(256) void k_wdn(const float* __restrict__ Wd, float* ws) {
    const int wave = threadIdx.x >> 6, lane = threadIdx.x & 63;
    const int f = blockIdx.x * 4 + wave;
    const float4 v = *reinterpret_cast<const float4*>(Wd + (size_t)f * DM + lane * 4);
    float s = v.x * v.x + v.y * v.y + v.z * v.z + v.w * v.w;
    #pragma unroll
    for (int o = 32; o; o >>= 1) s += __shfl_xor(s, o);
    if (lane == 0) ws[WS_WDN + f] = sqrtf(s);
}

__global__ void k_scale(const float* __restrict__ ravg, float* ws) {
    float ra = ALPHA_C * ravg[0] + (1.0f - ALPHA_C) * (ws[WS_RA] / (float)BATCH);
    ws[WS_SCALE] = 16.0f / ra;   // sqrt(256) = 16
}

// find segment boundary positions: bnd[s] = first feature of segment s
__global__ __launch_bounds__(256) void k_bnd(const int* __restrict__ seg, int* wsi) {
    const int f = blockIdx.x * 256 + threadIdx.x;
    if (f > 0 && f < NFEAT) {
        const int s = seg[f];
        if (s != seg[f - 1]) wsi[WSI_BND + s] = f;
    }
}

// build piece table: sorted dedup of {chunk starts} U {segment boundaries}
__global__ void k_pt(const int* __restrict__ seg, int* wsi) {
    int st[NCHUNK + NBLK - 1];
    int n = 0;
    for (int c = 0; c < NCHUNK; ++c) st[n++] = c * FC;
    for (int s = 1; s < NBLK; ++s) st[n++] = wsi[WSI_BND + s];
    for (int i = 1; i < n; ++i) {           // insertion sort
        int v = st[i]; int j = i - 1;
        while (j >= 0 && st[j] > v) { st[j + 1] = st[j]; --j; }
        st[j + 1] = v;
    }
    int N = 0;                               // dedup in place
    for (int i = 0; i < n; ++i)
        if (N == 0 || st[i] != st[N - 1]) st[N++] = st[i];
    wsi[WSI_PTN] = N;
    for (int i = 0; i < N; ++i) {
        wsi[WSI_PTS + i] = st[i];
        wsi[WSI_PSEG + i] = seg[st[i]];
    }
    wsi[WSI_PTS + N] = NFEAT;
}

// pack We [k][f] -> fragment order
__global__ __launch_bounds__(256) void k_packWe(const float* __restrict__ We,
                                                u16* __restrict__ WeP) {
    const int tid = blockIdx.x * 256 + threadIdx.x;
    const int l = tid & 63, kf = (tid >> 6) & 7, F = tid >> 9;
    const int f = F * 16 + (l & 15);
    const int kb = kf * 32 + (l >> 4) * 8;
    bf16x8 v;
    #pragma unroll
    for (int i = 0; i < 8; ++i)
        v[i] = (__bf16)We[(size_t)(kb + i) * NFEAT + f];
    *reinterpret_cast<bf16x8*>(WeP + (size_t)tid * 8) = v;
}

__global__ __launch_bounds__(256) void k_packWd(const float* __restrict__ Wd,
                                                u16* __restrict__ WdP) {
    const int tid = blockIdx.x * 256 + threadIdx.x;
    const int l = tid & 63, G = (tid >> 6) & 1023, Dg = tid >> 16;
    const int d = Dg * 16 + (l & 15);
    const int fb = G * 32 + (l >> 4) * 8;
    bf16x8 v;
    #pragma unroll
    for (int i = 0; i < 8; ++i)
        v[i] = (__bf16)Wd[(size_t)(fb + i) * DM + d];
    *reinterpret_cast<bf16x8*>(WdP + (size_t)tid * 8) = v;
}

// ---------------- fused main kernel ----------------
// grid (chunk=16, btile=32): linear id = chunk + 16*btile -> XCD = chunk%8.
// __launch_bounds__(512, 2): LDS (66 KB) caps at 2 blocks/CU = 4 waves/EU;
// VGPR cap 256 lets the allocator take the ~110-130 regs this kernel needs
// WITHOUT spilling (512,4 squeezed to 64 VGPR -> 570 MB scratch traffic).
__global__ __launch_bounds__(512, 2) void k_main(const float* __restrict__ x,
                                                 const float* __restrict__ be,
                                                 const int* __restrict__ seg,
                                                 float* __restrict__ ws,
                                                 u16* __restrict__ pieces,
                                                 const u16* __restrict__ WeP,
                                                 const u16* __restrict__ WdP) {
    __shared__ __align__(16) u16 xs[BT * DM];       // 32 KB packed
    __shared__ __align__(16) u16 acts[BT * MACRO];  // 32 KB packed
    __shared__ float lds_l1[NBLK];
    __shared__ unsigned lds_l0;
    __shared__ int s2s[NBLK];                       // seg -> piece slot (this chunk)

    const int t = threadIdx.x;
    const int w = t >> 6;           // 0..7
    const int l = t & 63;
    const int l15 = l & 15, lg = l >> 4;
    const int f0 = blockIdx.x * FC;
    const int b0 = blockIdx.y * BT;
    const float scale = ws[WS_SCALE];
    const int* wsi = (const int*)ws;

    if (t < NBLK) lds_l1[t] = 0.0f;
    if (t == 0) lds_l0 = 0u;
    if (t < NPMAX) {
        const int N = wsi[WSI_PTN];
        if (t < N) {
            const int ps = wsi[WSI_PTS + t];
            if (ps >= f0 && ps < f0 + FC) s2s[wsi[WSI_PSEG + t]] = t;
        }
    }

    // stage xn = x*scale, packed bf16
    #pragma unroll
    for (int p = 0; p < 8; ++p) {
        const int row = p * 8 + (t >> 6);
        const int col = (t & 63) * 4;
        const float4 v = *reinterpret_cast<const float4*>(x + (size_t)(b0 + row) * DM + col);
        bf16x4 h;
        h[0] = (__bf16)(v.x * scale); h[1] = (__bf16)(v.y * scale);
        h[2] = (__bf16)(v.z * scale); h[3] = (__bf16)(v.w * scale);
        const int e = (((row >> 4) * 8 + (col >> 5)) * 64 + ((col >> 3) & 3) * 16 + (row & 15)) * 8 + (col & 7);
        *reinterpret_cast<bf16x4*>(&xs[e]) = h;
    }
    __syncthreads();

    f32x4 pacc[4][2];
    #pragma unroll
    for (int i = 0; i < 4; ++i)
        #pragma unroll
        for (int j = 0; j < 2; ++j) pacc[i][j] = (f32x4)0.0f;

    int cur = seg[f0];
    float l1a = 0.0f;
    int myseg = -1;
    unsigned l0c = 0u;

    // store this segment's partial into its unique piece slot (sole writer)
    auto flush = [&](int s) {
        u16* pb = pieces + (size_t)s2s[s] * (BATCH * DM);
        #pragma unroll
        for (int rt = 0; rt < 4; ++rt)
            #pragma unroll
            for (int ct = 0; ct < 2; ++ct)
                #pragma unroll
                for (int r = 0; r < 4; ++r) {
                    const int row = b0 + 16 * rt + lg * 4 + r;
                    const int col = 32 * w + 16 * ct + l15;
                    pb[(size_t)row * DM + col] = f2b(pacc[rt][ct][r]);
                    pacc[rt][ct][r] = 0.0f;
                }
    };

    for (int ms = 0; ms < NMACRO; ++ms) {
        const int fbase = f0 + ms * MACRO;
        const bool uni = (seg[fbase] == seg[fbase + MACRO - 1]);

        // ---- encode (depth-2 B prefetch) ----
        f32x4 eacc[4][2];
        #pragma unroll
        for (int i = 0; i < 4; ++i)
            #pragma unroll
            for (int j = 0; j < 2; ++j) eacc[i][j] = (f32x4)0.0f;

        const int F0 = (fbase >> 4) + 2 * w;
        auto ldWe = [&](int kf, int ct) {
            return *reinterpret_cast<const bf16x8*>(WeP + (((size_t)(F0 + ct) * 8 + kf) * 64 + l) * 8);
        };
        bf16x8 bn0 = ldWe(0, 0), bn1 = ldWe(0, 1);
        #pragma unroll
        for (int kf = 0; kf < 8; ++kf) {
            const bf16x8 bc0 = bn0, bc1 = bn1;
            if (kf < 7) { bn0 = ldWe(kf + 1, 0); bn1 = ldWe(kf + 1, 1); }
            bf16x8 a[4];
            #pragma unroll
            for (int rt = 0; rt < 4; ++rt)
                a[rt] = *reinterpret_cast<const bf16x8*>(&xs[((rt * 8 + kf) * 64 + l) * 8]);
            #pragma unroll
            for (int rt = 0; rt < 4; ++rt) {
                eacc[rt][0] = mfma16(a[rt], bc0, eacc[rt][0]);
                eacc[rt][1] = mfma16(a[rt], bc1, eacc[rt][1]);
            }
        }

        // ---- epilogue: bias, relu, l1/l0, acts -> LDS packed bf16 ----
        #pragma unroll
        for (int ct = 0; ct < 2; ++ct) {
            const int fg = fbase + 32 * w + 16 * ct + l15;
            const float bias = be[fg];
            const float wdn10 = ws[WS_WDN + fg] * 10.0f;
            const int s = uni ? seg[fbase] : seg[fg];
            if (s != myseg) {
                if (myseg >= 0) atomicAdd(&lds_l1[myseg], l1a);
                l1a = 0.0f; myseg = s;
            }
            #pragma unroll
            for (int rt = 0; rt < 4; ++rt)
                #pragma unroll
                for (int r = 0; r < 4; ++r) {
                    float a = eacc[rt][ct][r] + bias;
                    a = fmaxf(a, 0.0f);
                    l0c += (a > 0.0f) ? 1u : 0u;
                    l1a += __logf(fmaf(a, wdn10, 1.0f));
                    const int e = ((rt * 8 + w) * 64 + ((16 * ct + l15) >> 3) * 16 + lg * 4 + r) * 8 + (l15 & 7);
                    acts[e] = f2b(a);
                }
        }
        __syncthreads();   // acts visible

        // ---- decode ----
        const int Dg0 = 2 * w;
        const int G0 = fbase >> 5;
        auto ldWd = [&](int kf, int ct) {
            return *reinterpret_cast<const bf16x8*>(WdP + (((size_t)(Dg0 + ct) * 1024 + G0 + kf) * 64 + l) * 8);
        };
        if (uni) {
            const int s = seg[fbase];
            if (s != cur) { flush(cur); cur = s; }
            bf16x8 dn0 = ldWd(0, 0), dn1 = ldWd(0, 1);
            #pragma unroll
            for (int kf = 0; kf < 8; ++kf) {
                const bf16x8 dc0 = dn0, dc1 = dn1;
                if (kf < 7) { dn0 = ldWd(kf + 1, 0); dn1 = ldWd(kf + 1, 1); }
                bf16x8 a[4];
                #pragma unroll
                for (int rt = 0; rt < 4; ++rt)
                    a[rt] = *reinterpret_cast<const bf16x8*>(&acts[((rt * 8 + kf) * 64 + l) * 8]);
                #pragma unroll
                for (int rt = 0; rt < 4; ++rt) {
                    pacc[rt][0] = mfma16(a[rt], dc0, pacc[rt][0]);
                    pacc[rt][1] = mfma16(a[rt], dc1, pacc[rt][1]);
                }
            }
        } else {
            for (int kf = 0; kf < 8; ++kf) {
                const int W0 = fbase + kf * 32;
                const int s0 = seg[W0], s1 = seg[W0 + 31];
                bf16x8 b[2];
                #pragma unroll
                for (int ct = 0; ct < 2; ++ct) b[ct] = ldWd(kf, ct);
                if (s0 == s1) {
                    if (s0 != cur) { flush(cur); cur = s0; }
                    bf16x8 a[4];
                    #pragma unroll
                    for (int rt = 0; rt < 4; ++rt)
                        a[rt] = *reinterpret_cast<const bf16x8*>(&acts[((rt * 8 + kf) * 64 + l) * 8]);
                    #pragma unroll
                    for (int rt = 0; rt < 4; ++rt) {
                        pacc[rt][0] = mfma16(a[rt], b[0], pacc[rt][0]);
                        pacc[rt][1] = mfma16(a[rt], b[1], pacc[rt][1]);
                    }
                } else {
                    int lo = 0;
                    while (lo < 32) {
                        const int s = seg[W0 + lo];
                        int hi = lo + 1;
                        while (hi < 32 && seg[W0 + hi] == s) ++hi;
                        if (s != cur) { flush(cur); cur = s; }
                        bf16x8 a[4];
                        #pragma unroll
                        for (int rt = 0; rt < 4; ++rt) {
                            a[rt] = *reinterpret_cast<const bf16x8*>(&acts[((rt * 8 + kf) * 64 + l) * 8]);
                            #pragma unroll
                            for (int i = 0; i < 8; ++i) {
                                const int kl = lg * 8 + i;
                                if (kl < lo || kl >= hi) a[rt][i] = (__bf16)0.0f;
                            }
                        }
                        #pragma unroll
                        for (int rt = 0; rt < 4; ++rt) {
                            pacc[rt][0] = mfma16(a[rt], b[0], pacc[rt][0]);
                            pacc[rt][1] = mfma16(a[rt], b[1], pacc[rt][1]);
                        }
                        lo = hi;
                    }
                }
            }
        }
        __syncthreads();   // decode reads done before next macro overwrites acts
    }

    flush(cur);
    if (myseg >= 0) atomicAdd(&lds_l1[myseg], l1a);
    atomicAdd(&lds_l0, l0c);
    __syncthreads();
    if (t < NBLK) atomicAdd(&ws[WS_L1 + t], lds_l1[t]);
    if (t == 0) atomicAdd(((unsigned*)ws) + WS_L0, lds_l0);
}

// ---------------- epilogue kernels ----------------

// walk pieces in feature order, accumulate cumsum, snapshot err at segment ends
__global__ __launch_bounds__(256) void k_err(const float* __restrict__ x,
                                             const float* __restrict__ bd,
                                             float* ws,
                                             const u16* __restrict__ pieces) {
    const int b = blockIdx.x, t = threadIdx.x;
    const int wave = t >> 6, lane = t & 63;
    const int* wsi = (const int*)ws;
    const int N = wsi[WSI_PTN];
    const float scale = ws[WS_SCALE];
    const float xv = x[(size_t)b * DM + t] * scale;
    float p = bd[t];
    __shared__ float lds[NBLK][4];
    for (int i = 0; i < N; ++i) {
        p += b2f(pieces[(size_t)i * (BATCH * DM) + (size_t)b * DM + t]);
        const int sg = wsi[WSI_PSEG + i];
        const bool end = (i == N - 1) || (wsi[WSI_PSEG + i + 1] != sg);
        if (end) {
            const float d = p - xv;
            float e = d * d;
            #pragma unroll
            for (int o = 32; o; o >>= 1) e += __shfl_xor(e, o);
            if (lane == 0) lds[sg][wave] = e;
        }
    }
    __syncthreads();
    if (t < NBLK) {
        const float s = lds[t][0] + lds[t][1] + lds[t][2] + lds[t][3];
        atomicAdd(&ws[WS_ERR + t], s);
    }
}

__global__ void k_loss(const float* __restrict__ bw,
                       const float* __restrict__ l1s,
                       const float* ws, float* out) {
    float cum = 0.0f, l1 = 0.0f, mse = 0.0f;
    for (int k = 0; k < NBLK; ++k) {
        cum += ws[WS_L1 + k] / (float)BATCH;
        l1 += bw[k] * cum;
        mse += bw[k] * (ws[WS_ERR + k] / (float)BATCH);
    }
    l1 *= (1.0f / NBLK);
    mse *= (1.0f / NBLK);
    const unsigned l0 = ((const unsigned*)ws)[WS_L0];
    const float avg_l0 = (float)l0 / (float)BATCH;
    const float rs = l1s[0] * (avg_l0 < TARGET_L0 ? (1.0f - EPS_CTRL) : (1.0f + EPS_CTRL));
    out[0] = mse + rs * l1;
}

// ---------------- launch ----------------

extern "C" void kernel_launch(void* const* d_in, const int* in_sizes, int n_in,
                              void* d_out, int out_size, void* d_ws, size_t ws_size,
                              hipStream_t stream) {
    const float* x    = (const float*)d_in[0];
    const float* We   = (const float*)d_in[1];
    const float* be   = (const float*)d_in[2];
    const float* Wd   = (const float*)d_in[3];
    const float* bd   = (const float*)d_in[4];
    const float* bw   = (const float*)d_in[5];
    const float* ravg = (const float*)d_in[6];
    const float* l1s  = (const float*)d_in[7];
    const int*   seg  = (const int*)d_in[8];
    float* out = (float*)d_out;
    float* ws  = (float*)d_ws;
    int*   wsi = (int*)d_ws;
    u16* pieces = (u16*)((char*)d_ws + PIECES_OFF_BYTES);
    u16* WeP = (u16*)((char*)d_ws + WEP_OFF_BYTES);
    u16* WdP = (u16*)((char*)d_ws + WDP_OFF_BYTES);

    hipMemsetAsync(d_ws, 0, 1024, stream);           // zero accumulators only
    k_bnd<<<NFEAT / 256, 256, 0, stream>>>(seg, wsi);
    k_pt<<<1, 1, 0, stream>>>(seg, wsi);
    k_rownorm<<<BATCH / 4, 256, 0, stream>>>(x, ws);
    k_wdn<<<NFEAT / 4, 256, 0, stream>>>(Wd, ws);
    k_packWe<<<(NFEAT / 16) * 8 * 64 / 256, 256, 0, stream>>>(We, WeP);
    k_packWd<<<(DM / 16) * (NFEAT / 32) * 64 / 256, 256, 0, stream>>>(Wd, WdP);
    k_scale<<<1, 1, 0, stream>>>(ravg, ws);
    dim3 g(NFEAT / FC, BATCH / BT);   // chunk-fast -> XCD = chunk%8 (L2-fit weights)
    k_main<<<g, 512, 0, stream>>>(x, be, seg, ws, pieces, WeP, WdP);
    k_err<<<BATCH, 256, 0, stream>>>(x, bd, ws, pieces);
    k_loss<<<1, 1, 0, stream>>>(bw, l1s, ws, out);
}